// Round 1
// baseline (1753.377 us; speedup 1.0000x reference)
//
#include <hip/hip_runtime.h>

#define B_ 64
#define S_ 2048
#define D_ 64
#define H_ 128
#define G_ 512
#define CH 16

typedef float f32x4 __attribute__((ext_vector_type(4)));
typedef short bf16x8 __attribute__((ext_vector_type(8)));

__device__ __forceinline__ short f2bf(float f) {
    unsigned u = __builtin_bit_cast(unsigned, f);
    unsigned r = (u + 0x7FFFu + ((u >> 16) & 1u)) >> 16;  // RNE
    return (short)r;
}
__device__ __forceinline__ float sigm(float x) { return 1.0f / (1.0f + __expf(-x)); }
__device__ __forceinline__ float tanh_(float x) {
    float ax = fabsf(x);
    float em = __expf(-2.0f * ax);
    float t = (1.0f - em) / (1.0f + em);
    return copysignf(t, x);
}

// One block per batch element. 512 threads = 8 waves.
// Wave w owns hidden units j in [16w, 16w+16); its 4 MFMA col-tiles are the
// i/f/g/o gate columns for exactly those units -> gating is wave-local.
// A-operand (h) is replicated across all 16 MFMA rows so the A row-map is
// a don't-care; A and B k-slots use the same packing so k-map errors cancel.
__launch_bounds__(512, 2)
__global__ void lstm_fused(const float* __restrict__ x, const float* __restrict__ Wx,
                           const float* __restrict__ Wh, const float* __restrict__ bias,
                           const float* __restrict__ Wd, const float* __restrict__ bd,
                           float* __restrict__ out) {
    const int tid = threadIdx.x;
    const int lane = tid & 63;
    const int wid = tid >> 6;      // 0..7
    const int l15 = lane & 15;
    const int l4 = lane >> 4;      // 0..3
    const int bb = blockIdx.x;     // batch index

    __shared__ alignas(16) short hbuf[2][H_];     // h (bf16), double-buffered by t parity
    __shared__ alignas(16) short xbf[CH * D_];    // current x chunk (bf16)
    __shared__ float xzc[CH][G_];                 // x@Wx + b for the chunk
    __shared__ float bsh[G_];
    __shared__ float ph[2][8];                    // head partials, dbuf by t parity

    bsh[tid] = bias[tid];
    if (tid < H_) { hbuf[0][tid] = 0; hbuf[1][tid] = 0; }

    // unit owned by this lane (replicated over the 4 lane-groups)
    const int col0 = wid * 16 + l15;

    // --- stage Wh into per-thread B-fragments (bf16), col = ct*128 + col0 ---
    bf16x8 bh[4][4];
#pragma unroll
    for (int ct = 0; ct < 4; ++ct) {
        const int col = ct * H_ + col0;
#pragma unroll
        for (int kt = 0; kt < 4; ++kt) {
            bf16x8 v;
#pragma unroll
            for (int e = 0; e < 8; ++e)
                v[e] = f2bf(Wh[(kt * 32 + l4 * 8 + e) * G_ + col]);
            bh[ct][kt] = v;
        }
    }
    // --- Wx B-fragments (K = 64 -> 2 k-tiles) ---
    bf16x8 bx[4][2];
#pragma unroll
    for (int ct = 0; ct < 4; ++ct) {
        const int col = ct * H_ + col0;
#pragma unroll
        for (int kt = 0; kt < 2; ++kt) {
            bf16x8 v;
#pragma unroll
            for (int e = 0; e < 8; ++e)
                v[e] = f2bf(Wx[(kt * 32 + l4 * 8 + e) * G_ + col]);
            bx[ct][kt] = v;
        }
    }

    const float wdv = Wd[col0];
    const float bdv = bd[0];
    float c_reg = 0.0f;

    const float* xb = x + (size_t)bb * S_ * D_;
    float* ob = out + (size_t)bb * S_;

    // prefetch x chunk 0 into registers (2 floats/thread = 16x64)
    float xp0 = xb[tid * 2 + 0];
    float xp1 = xb[tid * 2 + 1];

    __syncthreads();

    for (int t = 0; t < S_; ++t) {
        const int tm = t & (CH - 1);
        if (tm == 0) {
            // commit prefetched chunk to LDS
            xbf[tid * 2 + 0] = f2bf(xp0);
            xbf[tid * 2 + 1] = f2bf(xp1);
            __syncthreads();
            // prefetch next chunk (consumed 16 steps from now)
            if (t + CH < S_) {
                xp0 = xb[(t + CH) * D_ + tid * 2 + 0];
                xp1 = xb[(t + CH) * D_ + tid * 2 + 1];
            }
            // xz_chunk = X[16x64] @ Wx + b  (A rows = timesteps, M fully used)
#pragma unroll
            for (int ct = 0; ct < 4; ++ct) {
                const int col = ct * H_ + col0;
                const float bv = bsh[col];
                f32x4 acc = {bv, bv, bv, bv};
#pragma unroll
                for (int kt = 0; kt < 2; ++kt) {
                    const bf16x8 a = *reinterpret_cast<const bf16x8*>(
                        &xbf[l15 * D_ + kt * 32 + l4 * 8]);
                    acc = __builtin_amdgcn_mfma_f32_16x16x32_bf16(a, bx[ct][kt], acc, 0, 0, 0);
                }
#pragma unroll
                for (int r = 0; r < 4; ++r)
                    xzc[l4 * 4 + r][col] = acc[r];  // D row = (lane>>4)*4+reg [m89]
            }
            __syncthreads();
        }

        // ---- recurrent step: z = h @ Wh via MFMA, A replicated across rows ----
        const short* hsrc = hbuf[t & 1];
        bf16x8 af[4];
#pragma unroll
        for (int kt = 0; kt < 4; ++kt)
            af[kt] = *reinterpret_cast<const bf16x8*>(&hsrc[kt * 32 + l4 * 8]);

        f32x4 acc0 = {0.f, 0.f, 0.f, 0.f}, acc1 = acc0, acc2 = acc0, acc3 = acc0;
#pragma unroll
        for (int kt = 0; kt < 4; ++kt) {
            acc0 = __builtin_amdgcn_mfma_f32_16x16x32_bf16(af[kt], bh[0][kt], acc0, 0, 0, 0);
            acc1 = __builtin_amdgcn_mfma_f32_16x16x32_bf16(af[kt], bh[1][kt], acc1, 0, 0, 0);
            acc2 = __builtin_amdgcn_mfma_f32_16x16x32_bf16(af[kt], bh[2][kt], acc2, 0, 0, 0);
            acc3 = __builtin_amdgcn_mfma_f32_16x16x32_bf16(af[kt], bh[3][kt], acc3, 0, 0, 0);
        }

        // every row of D equals z (A replicated) -> use reg 0 in every lane
        const float zi = acc0[0] + xzc[tm][0 * H_ + col0];
        const float zf = acc1[0] + xzc[tm][1 * H_ + col0];
        const float zg = acc2[0] + xzc[tm][2 * H_ + col0];
        const float zo = acc3[0] + xzc[tm][3 * H_ + col0];

        const float ig = sigm(zi);
        const float fg = sigm(zf);
        const float gg = tanh_(zg);
        const float og = sigm(zo);
        c_reg = fg * c_reg + ig * gg;             // fp32 cell state, lane-resident
        const float hv = og * tanh_(c_reg);

        if (lane < 16) hbuf[(t + 1) & 1][col0] = f2bf(hv);

        // dense head partial: sum hv*Wd over this wave's 16 units
        float p = hv * wdv;
        p += __shfl_xor(p, 1);
        p += __shfl_xor(p, 2);
        p += __shfl_xor(p, 4);
        p += __shfl_xor(p, 8);
        if (lane == 0) ph[t & 1][wid] = p;

        __syncthreads();  // h_t visible to all waves; ph visible to thread 0

        if (tid == 0) {
            const float* q = ph[t & 1];
            float s = q[0] + q[1] + q[2] + q[3] + q[4] + q[5] + q[6] + q[7];
            ob[t] = sigm(s + bdv);
        }
    }
}

extern "C" void kernel_launch(void* const* d_in, const int* in_sizes, int n_in,
                              void* d_out, int out_size, void* d_ws, size_t ws_size,
                              hipStream_t stream) {
    const float* x  = (const float*)d_in[0];
    const float* Wx = (const float*)d_in[1];
    const float* Wh = (const float*)d_in[2];
    const float* b  = (const float*)d_in[3];
    const float* Wd = (const float*)d_in[4];
    const float* bd = (const float*)d_in[5];
    float* out = (float*)d_out;

    lstm_fused<<<B_, 512, 0, stream>>>(x, Wx, Wh, b, Wd, bd, out);
}

// Round 2
// 1086.066 us; speedup vs baseline: 1.6144x; 1.6144x over previous
//
#include <hip/hip_runtime.h>

#define B_ 64
#define S_ 2048
#define D_ 64
#define H_ 128
#define G_ 512
#define CH 16

typedef float f32x4 __attribute__((ext_vector_type(4)));
typedef short bf16x8 __attribute__((ext_vector_type(8)));

#define MFMA16(a, b, c) __builtin_amdgcn_mfma_f32_16x16x32_bf16((a), (b), (c), 0, 0, 0)

__device__ __forceinline__ short f2bf(float f) {
    unsigned u = __builtin_bit_cast(unsigned, f);
    return (short)((u + 0x7FFFu + ((u >> 16) & 1u)) >> 16);  // RNE
}
__device__ __forceinline__ float bflo(unsigned u) { return __builtin_bit_cast(float, u << 16); }
__device__ __forceinline__ float bfhi(unsigned u) { return __builtin_bit_cast(float, u & 0xFFFF0000u); }
// divisionless: v_rcp + native exp (v_exp). Saturation: exp->inf => rcp->0; exp->0 => rcp(1)=1.
__device__ __forceinline__ float sigm_f(float x) { return __builtin_amdgcn_rcpf(1.0f + __expf(-x)); }
__device__ __forceinline__ float tanh_f(float x) {
    return __builtin_amdgcn_rcpf(1.0f + __expf(-2.0f * x)) * 2.0f - 1.0f;
}

// One block per batch element; 512 threads = 8 waves.
// Wave w owns hidden units [16w,16w+16); gates for those units are wave-local.
// h kept as a 16-slot bf16 ring in LDS (doubles as history for the chunked
// dense-head reduction, which runs once per 16 steps instead of per step).
__launch_bounds__(512, 2)
__global__ void lstm_fused(const float* __restrict__ x, const float* __restrict__ Wx,
                           const float* __restrict__ Wh, const float* __restrict__ bias,
                           const float* __restrict__ Wd, const float* __restrict__ bd,
                           float* __restrict__ out) {
    const int tid = threadIdx.x;
    const int lane = tid & 63;
    const int wid = tid >> 6;      // 0..7
    const int l15 = lane & 15;
    const int l4 = lane >> 4;      // 0..3
    const int bb = blockIdx.x;

    __shared__ alignas(16) short hist[CH][H_];   // h ring (bf16), slot = t & 15
    __shared__ alignas(16) short xbf[CH][72];    // x chunk, padded to break bank conflicts
    __shared__ float xzc[CH][G_];                // x@Wx + b for current chunk

    // zero hist: 16*128 shorts = 1024 dwords
    ((unsigned*)hist)[tid] = 0u;
    ((unsigned*)hist)[tid + 512] = 0u;

    const int col0 = wid * 16 + l15;   // hidden unit owned by this lane (replicated over l4)

    // --- Wh B-fragments (bf16), col = ct*128 + col0, k = kt*32 + l4*8 + e ---
    bf16x8 bh[4][4];
#pragma unroll
    for (int ct = 0; ct < 4; ++ct) {
        const int col = ct * H_ + col0;
#pragma unroll
        for (int kt = 0; kt < 4; ++kt) {
            bf16x8 v;
#pragma unroll
            for (int e = 0; e < 8; ++e)
                v[e] = f2bf(Wh[(kt * 32 + l4 * 8 + e) * G_ + col]);
            bh[ct][kt] = v;
        }
    }
    // --- Wx B-fragments (K=64 -> 2 k-tiles) ---
    bf16x8 bx[4][2];
#pragma unroll
    for (int ct = 0; ct < 4; ++ct) {
        const int col = ct * H_ + col0;
#pragma unroll
        for (int kt = 0; kt < 2; ++kt) {
            bf16x8 v;
#pragma unroll
            for (int e = 0; e < 8; ++e)
                v[e] = f2bf(Wx[(kt * 32 + l4 * 8 + e) * G_ + col]);
            bx[ct][kt] = v;
        }
    }

    // per-lane constants in registers (no LDS)
    float bvr[4];
#pragma unroll
    for (int ct = 0; ct < 4; ++ct) bvr[ct] = bias[ct * H_ + col0];
    const float wd0 = Wd[lane * 2 + 0];
    const float wd1 = Wd[lane * 2 + 1];
    const float bdv = bd[0];
    float c_reg = 0.0f;

    const float* xb = x + (size_t)bb * S_ * D_;
    float* ob = out + (size_t)bb * S_;

    // prefetch x chunk 0 (2 floats/thread = 16x64)
    float xp0 = xb[tid * 2 + 0];
    float xp1 = xb[tid * 2 + 1];

    for (int t = 0; t < S_; ++t) {
        const int tm = t & (CH - 1);
        if (tm == 0) {
            // commit prefetched x chunk to LDS
            xbf[tid >> 5][(tid & 31) * 2 + 0] = f2bf(xp0);
            xbf[tid >> 5][(tid & 31) * 2 + 1] = f2bf(xp1);
            __syncthreads();   // xbf ready; hist writes from prior steps visible
            // prefetch next chunk
            if (t + CH < S_) {
                xp0 = xb[(t + CH) * D_ + tid * 2 + 0];
                xp1 = xb[(t + CH) * D_ + tid * 2 + 1];
            }
            // xz_chunk = X[16x64] @ Wx + b (A rows = timesteps)
#pragma unroll
            for (int ct = 0; ct < 4; ++ct) {
                f32x4 acc = {bvr[ct], bvr[ct], bvr[ct], bvr[ct]};
#pragma unroll
                for (int kt = 0; kt < 2; ++kt) {
                    const bf16x8 a = *reinterpret_cast<const bf16x8*>(
                        &xbf[l15][kt * 32 + l4 * 8]);
                    acc = MFMA16(a, bx[ct][kt], acc);
                }
                const int col = ct * H_ + col0;
#pragma unroll
                for (int r = 0; r < 4; ++r)
                    xzc[l4 * 4 + r][col] = acc[r];   // D row = (lane>>4)*4+reg [m89]
            }
            // dense head for the PREVIOUS 16 steps (hist slots 0..15 = h_{t-16..t-1})
            if (t > 0) {
#pragma unroll
                for (int s = 0; s < 2; ++s) {
                    const int row = wid * 2 + s;
                    const unsigned hp = *reinterpret_cast<const unsigned*>(&hist[row][lane * 2]);
                    float p = bflo(hp) * wd0 + bfhi(hp) * wd1;
                    p += __shfl_xor(p, 1);  p += __shfl_xor(p, 2);  p += __shfl_xor(p, 4);
                    p += __shfl_xor(p, 8);  p += __shfl_xor(p, 16); p += __shfl_xor(p, 32);
                    if (lane == 0) ob[t - CH + row] = sigm_f(p + bdv);
                }
            }
            __syncthreads();   // xzc ready; hist fully consumed before overwrite
        }

        // ---- recurrent step: z = h_{t-1} @ Wh, A replicated across M rows ----
        const short* hsrc = hist[(t + CH - 1) & (CH - 1)];
        const bf16x8 a0 = *reinterpret_cast<const bf16x8*>(&hsrc[ 0 + l4 * 8]);
        const bf16x8 a1 = *reinterpret_cast<const bf16x8*>(&hsrc[32 + l4 * 8]);
        const bf16x8 a2 = *reinterpret_cast<const bf16x8*>(&hsrc[64 + l4 * 8]);
        const bf16x8 a3 = *reinterpret_cast<const bf16x8*>(&hsrc[96 + l4 * 8]);
        const float xzi = xzc[tm][0 * H_ + col0];
        const float xzf = xzc[tm][1 * H_ + col0];
        const float xzg = xzc[tm][2 * H_ + col0];
        const float xzo = xzc[tm][3 * H_ + col0];

        // 2 independent 2-deep chains per gate (shorter dep chain, full pipelining)
        const f32x4 zz = {0.f, 0.f, 0.f, 0.f};
        f32x4 p0a = zz, p0b = zz, p1a = zz, p1b = zz, p2a = zz, p2b = zz, p3a = zz, p3b = zz;
        p0a = MFMA16(a0, bh[0][0], p0a);  p0b = MFMA16(a2, bh[0][2], p0b);
        p1a = MFMA16(a0, bh[1][0], p1a);  p1b = MFMA16(a2, bh[1][2], p1b);
        p2a = MFMA16(a0, bh[2][0], p2a);  p2b = MFMA16(a2, bh[2][2], p2b);
        p3a = MFMA16(a0, bh[3][0], p3a);  p3b = MFMA16(a2, bh[3][2], p3b);
        p0a = MFMA16(a1, bh[0][1], p0a);  p0b = MFMA16(a3, bh[0][3], p0b);
        p1a = MFMA16(a1, bh[1][1], p1a);  p1b = MFMA16(a3, bh[1][3], p1b);
        p2a = MFMA16(a1, bh[2][1], p2a);  p2b = MFMA16(a3, bh[2][3], p2b);
        p3a = MFMA16(a1, bh[3][1], p3a);  p3b = MFMA16(a3, bh[3][3], p3b);

        const float zi = p0a[0] + p0b[0] + xzi;   // every D row equals z (A replicated)
        const float zf = p1a[0] + p1b[0] + xzf;
        const float zg = p2a[0] + p2b[0] + xzg;
        const float zo = p3a[0] + p3b[0] + xzo;

        const float ig = sigm_f(zi);
        const float fg = sigm_f(zf);
        const float og = sigm_f(zo);
        const float gg = tanh_f(zg);
        c_reg = fg * c_reg + ig * gg;
        const float hv = og * tanh_f(c_reg);

        if (lane < 16) hist[tm][col0] = f2bf(hv);
        __syncthreads();   // h_t visible to all waves for step t+1
    }

    // dense head for the final 16 steps
#pragma unroll
    for (int s = 0; s < 2; ++s) {
        const int row = wid * 2 + s;
        const unsigned hp = *reinterpret_cast<const unsigned*>(&hist[row][lane * 2]);
        float p = bflo(hp) * wd0 + bfhi(hp) * wd1;
        p += __shfl_xor(p, 1);  p += __shfl_xor(p, 2);  p += __shfl_xor(p, 4);
        p += __shfl_xor(p, 8);  p += __shfl_xor(p, 16); p += __shfl_xor(p, 32);
        if (lane == 0) ob[S_ - CH + row] = sigm_f(p + bdv);
    }
}

extern "C" void kernel_launch(void* const* d_in, const int* in_sizes, int n_in,
                              void* d_out, int out_size, void* d_ws, size_t ws_size,
                              hipStream_t stream) {
    const float* x  = (const float*)d_in[0];
    const float* Wx = (const float*)d_in[1];
    const float* Wh = (const float*)d_in[2];
    const float* b  = (const float*)d_in[3];
    const float* Wd = (const float*)d_in[4];
    const float* bd = (const float*)d_in[5];
    float* out = (float*)d_out;

    lstm_fused<<<B_, 512, 0, stream>>>(x, Wx, Wh, b, Wd, bd, out);
}

// Round 3
// 1066.815 us; speedup vs baseline: 1.6436x; 1.0180x over previous
//
#include <hip/hip_runtime.h>

#define B_ 64
#define S_ 2048
#define D_ 64
#define H_ 128
#define G_ 512
#define CH 16

typedef float f32x4 __attribute__((ext_vector_type(4)));
typedef short bf16x8 __attribute__((ext_vector_type(8)));

#define MFMA16(a, b, c) __builtin_amdgcn_mfma_f32_16x16x32_bf16((a), (b), (c), 0, 0, 0)

#if __has_builtin(__builtin_amdgcn_exp2f)
#define EXP2(x) __builtin_amdgcn_exp2f(x)
#else
#define EXP2(x) exp2f(x)
#endif
#define RCPF(x) __builtin_amdgcn_rcpf(x)

#define LOG2E 1.442695041f

__device__ __forceinline__ short f2bf(float f) {
    unsigned u = __builtin_bit_cast(unsigned, f);
    return (short)((u + 0x7FFFu + ((u >> 16) & 1u)) >> 16);  // RNE
}
__device__ __forceinline__ float bflo(unsigned u) { return __builtin_bit_cast(float, u << 16); }
__device__ __forceinline__ float bfhi(unsigned u) { return __builtin_bit_cast(float, u & 0xFFFF0000u); }
__device__ __forceinline__ float sigm_f(float x) { return RCPF(1.0f + EXP2(x * -LOG2E)); }

// One block per batch element; 512 threads = 8 waves.
// Wave w owns hidden units [16w,16w+16). Gate-split across l4: lane (l4,l15)
// computes ONLY gate l4 for unit l15 via a unified chain
//   t = a*rcp(1+exp2(m*z)) + b   (sigma for l4 in {0,1,3}, tanh for l4==2)
// -> 2 transcendentals instead of 8; gates redistributed with 3 shfl_xor.
__launch_bounds__(512, 2)
__global__ void lstm_fused(const float* __restrict__ x, const float* __restrict__ Wx,
                           const float* __restrict__ Wh, const float* __restrict__ bias,
                           const float* __restrict__ Wd, const float* __restrict__ bd,
                           float* __restrict__ out) {
    const int tid = threadIdx.x;
    const int lane = tid & 63;
    const int wid = tid >> 6;      // 0..7
    const int l15 = lane & 15;
    const int l4 = lane >> 4;      // 0..3 == gate (i,f,g,o)
    const int bb = blockIdx.x;

    __shared__ alignas(16) short hist[CH][H_];   // h ring (bf16), slot = t & 15
    __shared__ alignas(16) short xbf[CH][72];    // x chunk (padded)
    __shared__ float xzc[CH][G_];                // layout: [tm][unit*4 + gate]

    ((unsigned*)hist)[tid] = 0u;
    ((unsigned*)hist)[tid + 512] = 0u;

    const int col0 = wid * 16 + l15;             // hidden unit
    const bool b0 = (l4 & 1) != 0;
    const bool b1 = (l4 & 2) != 0;

    // --- Wh B-fragments, col = ct*128 + col0, k = kt*32 + l4*8 + e ---
    bf16x8 bh[4][4];
#pragma unroll
    for (int ct = 0; ct < 4; ++ct) {
        const int col = ct * H_ + col0;
#pragma unroll
        for (int kt = 0; kt < 4; ++kt) {
            bf16x8 v;
#pragma unroll
            for (int e = 0; e < 8; ++e)
                v[e] = f2bf(Wh[(kt * 32 + l4 * 8 + e) * G_ + col]);
            bh[ct][kt] = v;
        }
    }
    // --- Wx B-fragments ---
    bf16x8 bx[4][2];
#pragma unroll
    for (int ct = 0; ct < 4; ++ct) {
        const int col = ct * H_ + col0;
#pragma unroll
        for (int kt = 0; kt < 2; ++kt) {
            bf16x8 v;
#pragma unroll
            for (int e = 0; e < 8; ++e)
                v[e] = f2bf(Wx[(kt * 32 + l4 * 8 + e) * G_ + col]);
            bx[ct][kt] = v;
        }
    }

    float bvr[4];
#pragma unroll
    for (int ct = 0; ct < 4; ++ct) bvr[ct] = bias[ct * H_ + col0];
    const float wd0 = Wd[lane * 2 + 0];
    const float wd1 = Wd[lane * 2 + 1];
    const float bdv = bd[0];
    float c_reg = 0.0f;

    // per-lane gate-function coefficients: t = a*rcp(1+exp2(m*z)) + b
    const float m_c = (l4 == 2) ? (-2.0f * LOG2E) : (-LOG2E);
    const float a_c = (l4 == 2) ? 2.0f : 1.0f;
    const float b_c = (l4 == 2) ? -1.0f : 0.0f;

    const float* xb = x + (size_t)bb * S_ * D_;
    float* ob = out + (size_t)bb * S_;

    float xp0 = xb[tid * 2 + 0];
    float xp1 = xb[tid * 2 + 1];

    for (int tc = 0; tc < S_; tc += CH) {
        // commit prefetched x chunk
        xbf[tid >> 5][(tid & 31) * 2 + 0] = f2bf(xp0);
        xbf[tid >> 5][(tid & 31) * 2 + 1] = f2bf(xp1);
        __syncthreads();
        if (tc + CH < S_) {
            xp0 = xb[(tc + CH) * D_ + tid * 2 + 0];
            xp1 = xb[(tc + CH) * D_ + tid * 2 + 1];
        }
        // xz_chunk = X[16x64] @ Wx + b -> interleaved layout [tm][unit*4+gate]
#pragma unroll
        for (int ct = 0; ct < 4; ++ct) {
            f32x4 acc = {bvr[ct], bvr[ct], bvr[ct], bvr[ct]};
#pragma unroll
            for (int kt = 0; kt < 2; ++kt) {
                const bf16x8 a = *reinterpret_cast<const bf16x8*>(&xbf[l15][kt * 32 + l4 * 8]);
                acc = MFMA16(a, bx[ct][kt], acc);
            }
#pragma unroll
            for (int r = 0; r < 4; ++r)
                xzc[l4 * 4 + r][col0 * 4 + ct] = acc[r];   // D row = (lane>>4)*4+r [m89]
        }
        // dense head for the PREVIOUS chunk (hist = h_{tc-16..tc-1})
        if (tc > 0) {
#pragma unroll
            for (int s = 0; s < 2; ++s) {
                const int row = wid * 2 + s;
                const unsigned hp = *reinterpret_cast<const unsigned*>(&hist[row][lane * 2]);
                float p = bflo(hp) * wd0 + bfhi(hp) * wd1;
                p += __shfl_xor(p, 1);  p += __shfl_xor(p, 2);  p += __shfl_xor(p, 4);
                p += __shfl_xor(p, 8);  p += __shfl_xor(p, 16); p += __shfl_xor(p, 32);
                if (lane == 0) ob[tc - CH + row] = sigm_f(p + bdv);
            }
        }
        __syncthreads();   // xzc ready; hist fully consumed before overwrite

#pragma unroll
        for (int tm = 0; tm < CH; ++tm) {
            const int prev = (tm + CH - 1) & (CH - 1);
            const short* hsrc = hist[prev];
            const bf16x8 a0 = *reinterpret_cast<const bf16x8*>(&hsrc[ 0 + l4 * 8]);
            const bf16x8 a1 = *reinterpret_cast<const bf16x8*>(&hsrc[32 + l4 * 8]);
            const bf16x8 a2 = *reinterpret_cast<const bf16x8*>(&hsrc[64 + l4 * 8]);
            const bf16x8 a3 = *reinterpret_cast<const bf16x8*>(&hsrc[96 + l4 * 8]);
            const float xz1 = xzc[tm][col0 * 4 + l4];   // only this lane's gate

            const f32x4 zz = {0.f, 0.f, 0.f, 0.f};
            f32x4 acc0 = zz, acc1 = zz, acc2 = zz, acc3 = zz;   // 4-deep chains
            acc0 = MFMA16(a0, bh[0][0], acc0);
            acc1 = MFMA16(a0, bh[1][0], acc1);
            acc2 = MFMA16(a0, bh[2][0], acc2);
            acc3 = MFMA16(a0, bh[3][0], acc3);
            acc0 = MFMA16(a1, bh[0][1], acc0);
            acc1 = MFMA16(a1, bh[1][1], acc1);
            acc2 = MFMA16(a1, bh[2][1], acc2);
            acc3 = MFMA16(a1, bh[3][1], acc3);
            acc0 = MFMA16(a2, bh[0][2], acc0);
            acc1 = MFMA16(a2, bh[1][2], acc1);
            acc2 = MFMA16(a2, bh[2][2], acc2);
            acc3 = MFMA16(a2, bh[3][2], acc3);
            acc0 = MFMA16(a3, bh[0][3], acc0);
            acc1 = MFMA16(a3, bh[1][3], acc1);
            acc2 = MFMA16(a3, bh[2][3], acc2);
            acc3 = MFMA16(a3, bh[3][3], acc3);

            // select this lane's gate z (A replicated -> row 0 valid everywhere)
            float zsel = b1 ? (b0 ? acc3[0] : acc2[0]) : (b0 ? acc1[0] : acc0[0]);
            zsel += xz1;

            // unified gate chain: 2 transcendentals for all 4 gates
            const float t = a_c * RCPF(1.0f + EXP2(zsel * m_c)) + b_c;

            // redistribute: lane gets all 4 gates of its unit
            const float r1 = __shfl_xor(t, 16);        // gate l4^1
            const float r2 = __shfl_xor(t, 32);        // gate l4^2
            const float r3 = __shfl_xor(r2, 16);       // gate l4^3
            const float iv = b1 ? (b0 ? r3 : r2) : (b0 ? r1 : t);
            const float fv = b1 ? (b0 ? r2 : r3) : (b0 ? t  : r1);
            const float gv = b1 ? (b0 ? r1 : t ) : (b0 ? r3 : r2);
            const float ov = b1 ? (b0 ? t  : r1) : (b0 ? r2 : r3);

            c_reg = fv * c_reg + iv * gv;
            const float th = 2.0f * RCPF(1.0f + EXP2(c_reg * (-2.0f * LOG2E))) - 1.0f;
            const float hv = ov * th;

            unsigned hb;
            asm("v_cvt_pk_bf16_f32 %0, %1, %2" : "=v"(hb) : "v"(hv), "v"(0.0f));
            if (lane < 16) hist[tm][col0] = (short)hb;
            __syncthreads();   // h_t visible to all waves for step t+1
        }
    }

    // dense head for the final 16 steps
#pragma unroll
    for (int s = 0; s < 2; ++s) {
        const int row = wid * 2 + s;
        const unsigned hp = *reinterpret_cast<const unsigned*>(&hist[row][lane * 2]);
        float p = bflo(hp) * wd0 + bfhi(hp) * wd1;
        p += __shfl_xor(p, 1);  p += __shfl_xor(p, 2);  p += __shfl_xor(p, 4);
        p += __shfl_xor(p, 8);  p += __shfl_xor(p, 16); p += __shfl_xor(p, 32);
        if (lane == 0) ob[S_ - CH + row] = sigm_f(p + bdv);
    }
}

extern "C" void kernel_launch(void* const* d_in, const int* in_sizes, int n_in,
                              void* d_out, int out_size, void* d_ws, size_t ws_size,
                              hipStream_t stream) {
    const float* x  = (const float*)d_in[0];
    const float* Wx = (const float*)d_in[1];
    const float* Wh = (const float*)d_in[2];
    const float* b  = (const float*)d_in[3];
    const float* Wd = (const float*)d_in[4];
    const float* bd = (const float*)d_in[5];
    float* out = (float*)d_out;

    lstm_fused<<<B_, 512, 0, stream>>>(x, Wx, Wh, b, Wd, bd, out);
}